// Round 1
// baseline (568.861 us; speedup 1.0000x reference)
//
#include <hip/hip_runtime.h>

// out_fp = (a*scale_a)*(b*scale_b); out_q = clip(rint(out_fp/scale_out), -128, 127)
// a,b int8-in-reference delivered as int32 (const int*), N = 16*4096*1024 = 67108864.
// scales float32 (D=1024). d_out = float[N] quantized values ++ float[D] scale_out.
//
// R1: simple 1x int4-pair/thread, plain ld/st -> 176 us, 4.6 TB/s demand.
// R3: UNROLL4 + nt STORES -> 208 us regression (CONFOUNDED: unroll and nt-store
//     changed together; journal blamed nt stores).
// R4: R1 structure + nt LOADS only -> bench 558 us; mulq below rocprof top-5
//     (<163 us), ~5.0 TB/s demand. Poison fills show 6.4-6.5 TB/s achievable.
// R5 (this): ILP-4, plain stores (isolates unroll from nt-store confound).
//     Thread's 4 vec4s are 256 vec4 = 1024 elem = D apart -> same column ->
//     one c-table load reused 4x; 8 nt dwordx4 loads in flight per thread.
//     __mul24 for the int8-range product (full-rate vs quarter-rate mul_lo).
//     Predict mulq ~130-145 us, dur_us ~440-490.

typedef int   vi4 __attribute__((ext_vector_type(4)));
typedef float vf4 __attribute__((ext_vector_type(4)));

#define TPB   256
#define ITERS 4
#define VPB   (TPB * ITERS)   // vec4s per block = 1024 (4096 elements)

__global__ void prep_scales_kernel(const float* __restrict__ sa,
                                   const float* __restrict__ sb,
                                   const float* __restrict__ so,
                                   float* __restrict__ c,
                                   float* __restrict__ out_tail,
                                   int D) {
    int d = blockIdx.x * blockDim.x + threadIdx.x;
    if (d < D) {
        float s = so[d];
        c[d] = sa[d] * sb[d] / s;   // exact IEEE divide, once per column
        out_tail[d] = s;            // second tuple output: scale_out passthrough
    }
}

__device__ __forceinline__ float qclamp(int p, float cs) {
    return fminf(fmaxf(rintf((float)p * cs), -128.0f), 127.0f);
}

__global__ __launch_bounds__(TPB) void mulq4_kernel(const vi4* __restrict__ a,
                                                    const vi4* __restrict__ b,
                                                    const float* __restrict__ c,
                                                    vf4* __restrict__ out,
                                                    unsigned dmask, unsigned use_mask,
                                                    unsigned D, unsigned dreuse,
                                                    unsigned nvec) {
    unsigned base = blockIdx.x * (unsigned)VPB + threadIdx.x;
    unsigned e0 = base * 4u;  // first element index of iteration 0

    if (base + (unsigned)(TPB * (ITERS - 1)) < nvec) {
        // ---- fast path: all 4 vec4s in range ----
        // c-table load first (L1-hot 4 KiB), then all 8 streaming loads.
        float4 cv0 = *(const float4*)(c + (use_mask ? (e0 & dmask) : (e0 % D)));

        vi4 av[ITERS], bv[ITERS];
#pragma unroll
        for (int i = 0; i < ITERS; ++i) {
            av[i] = __builtin_nontemporal_load(&a[base + (unsigned)(TPB * i)]);
            bv[i] = __builtin_nontemporal_load(&b[base + (unsigned)(TPB * i)]);
        }

#pragma unroll
        for (int i = 0; i < ITERS; ++i) {
            float4 cv;
            if (i == 0 || dreuse) {
                cv = cv0;   // iterations are (TPB*4)=1024 elements apart: same column when 1024 % D == 0
            } else {
                unsigned ei = e0 + (unsigned)(TPB * 4 * i);
                cv = *(const float4*)(c + (use_mask ? (ei & dmask) : (ei % D)));
            }
            vf4 o;
            o.x = qclamp(__mul24(av[i].x, bv[i].x), cv.x);
            o.y = qclamp(__mul24(av[i].y, bv[i].y), cv.y);
            o.z = qclamp(__mul24(av[i].z, bv[i].z), cv.z);
            o.w = qclamp(__mul24(av[i].w, bv[i].w), cv.w);
            out[base + (unsigned)(TPB * i)] = o;     // plain store (L3-friendly)
        }
    } else {
        // ---- tail path (never taken at N=2^26, kept for generality) ----
        for (int i = 0; i < ITERS; ++i) {
            unsigned idx = base + (unsigned)(TPB * i);
            if (idx >= nvec) break;                  // idx monotone increasing
            unsigned ei = idx * 4u;
            unsigned d  = use_mask ? (ei & dmask) : (ei % D);
            vi4 av = __builtin_nontemporal_load(&a[idx]);
            vi4 bv = __builtin_nontemporal_load(&b[idx]);
            float4 cv = *(const float4*)(c + d);
            vf4 o;
            o.x = qclamp(__mul24(av.x, bv.x), cv.x);
            o.y = qclamp(__mul24(av.y, bv.y), cv.y);
            o.z = qclamp(__mul24(av.z, bv.z), cv.z);
            o.w = qclamp(__mul24(av.w, bv.w), cv.w);
            out[idx] = o;
        }
    }
}

extern "C" void kernel_launch(void* const* d_in, const int* in_sizes, int n_in,
                              void* d_out, int out_size, void* d_ws, size_t ws_size,
                              hipStream_t stream) {
    const int*   a  = (const int*)  d_in[0];
    const float* sa = (const float*)d_in[1];
    const int*   b  = (const int*)  d_in[2];
    const float* sb = (const float*)d_in[3];
    const float* so = (const float*)d_in[4];

    const int N = in_sizes[0];   // 67108864
    const int D = in_sizes[1];   // 1024

    float* out = (float*)d_out;
    float* c   = (float*)d_ws;   // D floats of scratch (4 KiB)

    prep_scales_kernel<<<(D + 255) / 256, 256, 0, stream>>>(sa, sb, so, c, out + (size_t)N, D);

    const unsigned nvec     = (unsigned)(N / 4);
    const unsigned use_mask = ((D & (D - 1)) == 0) ? 1u : 0u;
    // a thread's successive iterations are TPB*4 = 1024 elements apart;
    // if 1024 % D == 0 the column index is identical across iterations.
    const unsigned dreuse   = ((1024u % (unsigned)D) == 0u) ? 1u : 0u;
    const unsigned nblocks  = (nvec + (unsigned)VPB - 1u) / (unsigned)VPB;

    mulq4_kernel<<<nblocks, TPB, 0, stream>>>(
        (const vi4*)a, (const vi4*)b, c, (vf4*)out,
        (unsigned)(D - 1), use_mask, (unsigned)D, dreuse, nvec);
}